// Round 5
// baseline (50.271 us; speedup 1.0000x reference)
//
#include <hip/hip_runtime.h>

// InfoNCE-on-image-norms, single fused kernel, FENCE-FREE last-block pattern.
// R2 lesson: __threadfence() (agent release fence) per block = L2 writeback
// storm (230us). Fix: all cross-block traffic goes through atomic RMWs,
// which operate at the device coherence point (m20: atomicAdd is
// device-scope by default) -- no cache maintenance instructions at all.
//   Phase 1: 128 images x 21 chunks = 2688 blocks x 256 thr; each thread
//            7 coalesced float4 loads -> sumsq; shuffle+LDS block reduce;
//            thread 0: atomicAdd(acc[img], partial); s_waitcnt vmcnt(0);
//            atomicAdd(counter, 1).
//   Phase 2: last block reads acc[] via fetch_add(+0.0) RMWs (coherent),
//            computes mu/std (ddof=0) + exp/log loss in double.

#define IMG_ELEMS   150528          // 3*224*224
#define VEC_PER_IMG 37632           // IMG_ELEMS/4
#define CHUNKS      21
#define VEC_PER_CHK 1792            // 37632/21
#define ITERS       7               // 1792/256
#define NBLOCKS     (128 * CHUNKS)  // 2688
#define TEMPERATURE 0.7

__global__ __launch_bounds__(256) void infonce_fused(const float* __restrict__ pos,
                                                     const float* __restrict__ neg,
                                                     unsigned int* __restrict__ counter,
                                                     float* __restrict__ acc,
                                                     float* __restrict__ out) {
    const int bid   = blockIdx.x;          // 0..2687
    const int img   = bid / CHUNKS;        // 0..127
    const int chunk = bid % CHUNKS;        // 0..20
    const int tid   = threadIdx.x;

    const float* base = (img < 64) ? (pos + (size_t)img * IMG_ELEMS)
                                   : (neg + (size_t)(img - 64) * IMG_ELEMS);
    const float4* src = (const float4*)base;

    const int idx0 = chunk * VEC_PER_CHK + tid;
    float a = 0.0f;
#pragma unroll
    for (int i = 0; i < ITERS; ++i) {
        float4 v = src[idx0 + i * 256];
        a += v.x * v.x + v.y * v.y + v.z * v.z + v.w * v.w;
    }

    // 64-lane wave reduction
#pragma unroll
    for (int off = 32; off > 0; off >>= 1)
        a += __shfl_down(a, off, 64);

    __shared__ float lds[4];
    __shared__ int   last_flag;
    const int wave = tid >> 6;
    const int lane = tid & 63;
    if (lane == 0) lds[wave] = a;
    __syncthreads();

    if (tid == 0) {
        float partial = lds[0] + lds[1] + lds[2] + lds[3];
        atomicAdd(&acc[img], partial);                 // device-scope RMW (m20)
        asm volatile("s_waitcnt vmcnt(0)" ::: "memory"); // drain: add performed
        unsigned int old = atomicAdd(counter, 1u);     // coherent counter
        last_flag = (old == NBLOCKS - 1) ? 1 : 0;
    }
    __syncthreads();
    if (!last_flag) return;

    // ---- Phase 2: last block only (256 threads; t<128 own image t) ----
    const int t = tid;
    double norm = 0.0;
    if (t < 128) {
        // RMW read: performed at the coherence point, sees all adds.
        float s = atomicAdd(&acc[t], 0.0f);
        norm = sqrt((double)s);
    }

    double sum = norm, sumsq = norm * norm;
#pragma unroll
    for (int off = 32; off > 0; off >>= 1) {
        sum   += __shfl_down(sum,   off, 64);
        sumsq += __shfl_down(sumsq, off, 64);
    }
    __shared__ double red[8];
    if (lane == 0) { red[wave * 2] = sum; red[wave * 2 + 1] = sumsq; }
    __syncthreads();

    const double tot   = red[0] + red[2];   // waves 2,3 contribute zero
    const double totsq = red[1] + red[3];
    const double mu    = tot / 128.0;
    double var         = totsq / 128.0 - mu * mu;
    if (var < 0.0) var = 0.0;
    const double denom = sqrt(var) * TEMPERATURE;

    double e = (t < 128) ? exp((norm - mu) / denom) : 0.0;
#pragma unroll
    for (int off = 32; off > 0; off >>= 1)
        e += __shfl_down(e, off, 64);

    __shared__ double sims[4];
    if (lane == 0) sims[wave] = e;
    __syncthreads();

    if (t == 0) {
        const double ps = sims[0];
        const double ns = sims[1];
        out[0] = (float)(-log(ps / (ps + ns)));
    }
}

extern "C" void kernel_launch(void* const* d_in, const int* in_sizes, int n_in,
                              void* d_out, int out_size, void* d_ws, size_t ws_size,
                              hipStream_t stream) {
    const float* pos = (const float*)d_in[0];
    const float* neg = (const float*)d_in[1];

    unsigned int* counter = (unsigned int*)d_ws;              // 4 B
    float* acc            = (float*)((char*)d_ws + 128);      // 128 floats
    float* out            = (float*)d_out;

    // zero counter + accumulators (capture-legal memset node)
    hipMemsetAsync(d_ws, 0, 128 + 128 * sizeof(float), stream);
    infonce_fused<<<NBLOCKS, 256, 0, stream>>>(pos, neg, counter, acc, out);
}

// Round 6
// 24.185 us; speedup vs baseline: 2.0786x; 2.0786x over previous
//
#include <hip/hip_runtime.h>

// InfoNCE-on-image-norms, fused, fence-free, TWO-LEVEL counter tree.
// R2: per-block agent release fences -> 230us L2 writeback storm. R5: single
// counter address x 2688 RMWs -> ~30us same-address atomic serialization.
// Fix: per-image counters (21 RMWs each, parallel across 128 padded
// addresses), winner of each image bumps the global done counter (128 RMWs).
// All cross-block data goes through atomic RMWs at the device coherence
// point; ordering via per-block vmcnt(0) drain + atomic return-value deps.

#define IMG_ELEMS   150528          // 3*224*224
#define CHUNKS      21
#define VEC_PER_CHK 1792            // 37632/21
#define ITERS       7               // 1792/256
#define NBLOCKS     (128 * CHUNKS)  // 2688
#define TEMPERATURE 0.7
#define PAD         16              // 16 x 4B = 64B stride (one cacheline)

__global__ __launch_bounds__(256) void infonce_fused(const float* __restrict__ pos,
                                                     const float* __restrict__ neg,
                                                     unsigned int* __restrict__ done,
                                                     unsigned int* __restrict__ imgcnt,
                                                     float* __restrict__ acc,
                                                     float* __restrict__ out) {
    const int bid   = blockIdx.x;          // 0..2687
    const int img   = bid / CHUNKS;        // 0..127
    const int chunk = bid % CHUNKS;        // 0..20
    const int tid   = threadIdx.x;

    const float* base = (img < 64) ? (pos + (size_t)img * IMG_ELEMS)
                                   : (neg + (size_t)(img - 64) * IMG_ELEMS);
    const float4* src = (const float4*)base;

    const int idx0 = chunk * VEC_PER_CHK + tid;
    float a = 0.0f;
#pragma unroll
    for (int i = 0; i < ITERS; ++i) {
        float4 v = src[idx0 + i * 256];
        a += v.x * v.x + v.y * v.y + v.z * v.z + v.w * v.w;
    }

    // 64-lane wave reduction
#pragma unroll
    for (int off = 32; off > 0; off >>= 1)
        a += __shfl_down(a, off, 64);

    __shared__ float lds[4];
    __shared__ int   last_flag;
    const int wave = tid >> 6;
    const int lane = tid & 63;
    if (lane == 0) lds[wave] = a;
    __syncthreads();

    if (tid == 0) {
        float partial = lds[0] + lds[1] + lds[2] + lds[3];
        atomicAdd(&acc[img * PAD], partial);               // coherent RMW
        asm volatile("s_waitcnt vmcnt(0)" ::: "memory");   // acc-add performed
        int lf = 0;
        unsigned int oc = atomicAdd(&imgcnt[img * PAD], 1u);  // 21-way fan-in
        if (oc == CHUNKS - 1) {                               // image complete
            unsigned int od = atomicAdd(done, 1u);            // 128-way fan-in
            lf = (od == 127) ? 1 : 0;                         // grid complete
        }
        last_flag = lf;
    }
    __syncthreads();
    if (!last_flag) return;

    // ---- Phase 2: exactly one block reaches here (256 threads) ----
    const int t = tid;
    double norm = 0.0;
    if (t < 128) {
        float s = atomicAdd(&acc[t * PAD], 0.0f);   // RMW read at coherence point
        norm = sqrt((double)s);
    }

    double sum = norm, sumsq = norm * norm;
#pragma unroll
    for (int off = 32; off > 0; off >>= 1) {
        sum   += __shfl_down(sum,   off, 64);
        sumsq += __shfl_down(sumsq, off, 64);
    }
    __shared__ double red[8];
    if (lane == 0) { red[wave * 2] = sum; red[wave * 2 + 1] = sumsq; }
    __syncthreads();

    const double tot   = red[0] + red[2];   // waves 2,3 contribute zero
    const double totsq = red[1] + red[3];
    const double mu    = tot / 128.0;
    double var         = totsq / 128.0 - mu * mu;
    if (var < 0.0) var = 0.0;
    const double denom = sqrt(var) * TEMPERATURE;

    double e = (t < 128) ? exp((norm - mu) / denom) : 0.0;
#pragma unroll
    for (int off = 32; off > 0; off >>= 1)
        e += __shfl_down(e, off, 64);

    __shared__ double sims[4];
    if (lane == 0) sims[wave] = e;
    __syncthreads();

    if (t == 0) {
        const double ps = sims[0];
        const double ns = sims[1];
        out[0] = (float)(-log(ps / (ps + ns)));
    }
}

extern "C" void kernel_launch(void* const* d_in, const int* in_sizes, int n_in,
                              void* d_out, int out_size, void* d_ws, size_t ws_size,
                              hipStream_t stream) {
    const float* pos = (const float*)d_in[0];
    const float* neg = (const float*)d_in[1];

    // ws layout: [0,128)   done counter (own cacheline)
    //            [128, 128+8192)        imgcnt[128] @ 64B stride
    //            [8320, 8320+8192)      acc[128]    @ 64B stride
    unsigned int* done   = (unsigned int*)d_ws;
    unsigned int* imgcnt = (unsigned int*)((char*)d_ws + 128);
    float*        acc    = (float*)((char*)d_ws + 8320);
    float*        out    = (float*)d_out;

    hipMemsetAsync(d_ws, 0, 16512, stream);   // capture-legal memset node
    infonce_fused<<<NBLOCKS, 256, 0, stream>>>(pos, neg, done, imgcnt, acc, out);
}

// Round 9
// 19.273 us; speedup vs baseline: 2.6083x; 1.2549x over previous
//
#include <hip/hip_runtime.h>

// InfoNCE-on-image-norms, two-kernel (fence-free) version — proven R3 config.
//   Stage 1: 128 images x 21 chunks = 2688 blocks x 256 thr; each thread
//            7 coalesced float4 loads -> sum of squares; wave shuffle
//            reduce + LDS -> one float partial per block (plain store).
//   Stage 2: 1 block x 128 thr; thread t sums image t's 21 partials,
//            sqrt -> norm; mu/std (ddof=0) + exp/log loss in double.
// Kernel boundary provides cross-XCD visibility -- no fences, no atomics.
//
// Ladder history: R2 per-block agent fences = 230us (L2 writeback storm);
// R5 single-counter fan-in = 50us (same-address RMW serialization);
// R6 two-level tree + memset = 24.2us; R7/R8 init-free modular-winner =
// WRONG (unique but not LAST -> early winner reads unpublished partials).
// Two-kernel 19.2us is the measured floor: fixed replay overhead ~7.4us +
// BW-bound stage-1 ~7.8us (block-count/depth insensitive) + dispatch+gap.

#define IMG_ELEMS   150528          // 3*224*224
#define VEC_PER_IMG 37632           // IMG_ELEMS/4
#define CHUNKS      21
#define VEC_PER_CHK 1792            // 37632/21
#define ITERS       7               // 1792/256
#define TEMPERATURE 0.7

__global__ __launch_bounds__(256) void sumsq_kernel(const float* __restrict__ pos,
                                                    const float* __restrict__ neg,
                                                    float* __restrict__ partials) {
    const int bid   = blockIdx.x;          // 0..2687
    const int img   = bid / CHUNKS;        // 0..127
    const int chunk = bid % CHUNKS;        // 0..20

    const float* base = (img < 64) ? (pos + (size_t)img * IMG_ELEMS)
                                   : (neg + (size_t)(img - 64) * IMG_ELEMS);
    const float4* src = (const float4*)base;

    int idx = chunk * VEC_PER_CHK + threadIdx.x;
    float acc = 0.0f;
#pragma unroll
    for (int i = 0; i < ITERS; ++i) {
        float4 v = src[idx + i * 256];
        acc += v.x * v.x + v.y * v.y + v.z * v.z + v.w * v.w;
    }

    // 64-lane wave reduction
#pragma unroll
    for (int off = 32; off > 0; off >>= 1)
        acc += __shfl_down(acc, off, 64);

    __shared__ float lds[4];
    const int wave = threadIdx.x >> 6;
    const int lane = threadIdx.x & 63;
    if (lane == 0) lds[wave] = acc;
    __syncthreads();
    if (threadIdx.x == 0)
        partials[bid] = lds[0] + lds[1] + lds[2] + lds[3];
}

__global__ __launch_bounds__(128) void loss_kernel(const float* __restrict__ partials,
                                                   float* __restrict__ out) {
    const int t = threadIdx.x;             // 0..127 ; wave0 = pos, wave1 = neg
    const int wave = t >> 6;
    const int lane = t & 63;

    float s = 0.0f;
#pragma unroll
    for (int i = 0; i < CHUNKS; ++i) s += partials[t * CHUNKS + i];
    const double norm = sqrt((double)s);

    // mean / E[x^2] over all 128 norms (double)
    double sum = norm, sumsq = norm * norm;
#pragma unroll
    for (int off = 32; off > 0; off >>= 1) {
        sum   += __shfl_down(sum,   off, 64);
        sumsq += __shfl_down(sumsq, off, 64);
    }
    __shared__ double red[4];
    if (lane == 0) { red[wave * 2] = sum; red[wave * 2 + 1] = sumsq; }
    __syncthreads();

    const double tot   = red[0] + red[2];
    const double totsq = red[1] + red[3];
    const double mu    = tot / 128.0;
    double var         = totsq / 128.0 - mu * mu;
    if (var < 0.0) var = 0.0;
    const double denom = sqrt(var) * TEMPERATURE;

    const double e = exp((norm - mu) / denom);

    // per-wave sum: wave0 -> pos_sim, wave1 -> neg_sim
    double esum = e;
#pragma unroll
    for (int off = 32; off > 0; off >>= 1)
        esum += __shfl_down(esum, off, 64);

    __shared__ double sims[2];
    if (lane == 0) sims[wave] = esum;
    __syncthreads();

    if (t == 0) {
        const double ps = sims[0];
        const double ns = sims[1];
        out[0] = (float)(-log(ps / (ps + ns)));
    }
}

extern "C" void kernel_launch(void* const* d_in, const int* in_sizes, int n_in,
                              void* d_out, int out_size, void* d_ws, size_t ws_size,
                              hipStream_t stream) {
    const float* pos = (const float*)d_in[0];
    const float* neg = (const float*)d_in[1];
    float* partials  = (float*)d_ws;        // 2688 floats
    float* out       = (float*)d_out;       // 1 float

    sumsq_kernel<<<128 * CHUNKS, 256, 0, stream>>>(pos, neg, partials);
    loss_kernel<<<1, 128, 0, stream>>>(partials, out);
}